// Round 10
// baseline (570.184 us; speedup 1.0000x reference)
//
#include <hip/hip_runtime.h>
#include <hip/hip_bf16.h>
#include <stdint.h>

#define B_ 128
#define S_ 512
#define H_ 1024
#define E_ 1024
#define V_ 50000
#define EXTRA_ 500
#define VE_ 50500
#define EPS_ 1e-8f

typedef __attribute__((ext_vector_type(4))) float f32x4;
typedef __attribute__((ext_vector_type(8))) short bf16x8;

__device__ __forceinline__ unsigned short f2bf(float f) {
    unsigned u = __builtin_bit_cast(unsigned, f);
    u = (u + 0x7FFFu + ((u >> 16) & 1u)) >> 16;
    return (unsigned short)u;
}

__device__ __forceinline__ bf16x8 pack8(const float* f) {
    union { bf16x8 v; unsigned short s[8]; } u;
#pragma unroll
    for (int i = 0; i < 8; ++i) u.s[i] = f2bf(f[i]);
    return u.v;
}

__device__ __forceinline__ float bf2f(unsigned short s) {
    unsigned u = (unsigned)s << 16;
    return __builtin_bit_cast(float, u);
}

__device__ __forceinline__ float fast_tanh(float x) {
    x = fminf(fmaxf(x, -15.f), 15.f);
    float e = __expf(2.f * x);
    return __fdividef(e - 1.f, e + 1.f);
}

// async global->LDS, 16 bytes per lane; lds dest is wave-uniform-base + lane*16
__device__ __forceinline__ void gload16(const void* g, void* l) {
    __builtin_amdgcn_global_load_lds(
        reinterpret_cast<const __attribute__((address_space(1))) unsigned int*>(
            reinterpret_cast<uintptr_t>(g)),
        reinterpret_cast<__attribute__((address_space(3))) unsigned int*>(
            reinterpret_cast<uintptr_t>(l)),
        16, 0, 0);
}

// ---------------- K0: f32 -> bf16 convert ----------------
__global__ __launch_bounds__(256) void cvt_bf16_kernel(const float* __restrict__ in,
                                                       unsigned short* __restrict__ out) {
    int i = (blockIdx.x * 256 + threadIdx.x) * 8;
    float f[8];
    *(float4*)f     = *(const float4*)(in + i);
    *(float4*)(f+4) = *(const float4*)(in + i + 4);
    union { uint4 v; unsigned short s[8]; } u;
#pragma unroll
    for (int j = 0; j < 8; ++j) u.s[j] = f2bf(f[j]);
    *(uint4*)(out + i) = u.v;
}

// ---------------- K1: embedding + layernorm + concat ----------------
__global__ __launch_bounds__(256) void embed_ln_kernel(
    const int* __restrict__ tok, const float* __restrict__ embed,
    const float* __restrict__ g, const float* __restrict__ beta,
    const float* __restrict__ ctx, float* __restrict__ x_cat)
{
    __shared__ float red[256];
    int b = blockIdx.x, t = threadIdx.x;
    const float* row = embed + (size_t)tok[b] * E_;
    float v[4];
    float s = 0.f;
#pragma unroll
    for (int i = 0; i < 4; ++i) { v[i] = row[t + i*256]; s += v[i]; }
    red[t] = s; __syncthreads();
    for (int o = 128; o > 0; o >>= 1) { if (t < o) red[t] += red[t+o]; __syncthreads(); }
    float mu = red[0] * (1.f/E_);
    __syncthreads();
    s = 0.f;
#pragma unroll
    for (int i = 0; i < 4; ++i) { float d = v[i]-mu; s += d*d; }
    red[t] = s; __syncthreads();
    for (int o = 128; o > 0; o >>= 1) { if (t < o) red[t] += red[t+o]; __syncthreads(); }
    float inv = rsqrtf(red[0]*(1.f/E_) + 1e-5f);
    float* xrow = x_cat + (size_t)b * 2048;
#pragma unroll
    for (int i = 0; i < 4; ++i) {
        int j = t + i*256;
        xrow[j] = (v[i]-mu)*inv*g[j] + beta[j];
        xrow[1024 + j] = ctx[b*1024 + j];
    }
}

// ---------------- generic M=128 GEMM with K-split + A-partial-sum ----------------
// slice y==0 writes C (+bias); y>0 writes C1 + (y-1)*128*ldc.
// aparts: A is the elementwise sum of `aparts` slices at stride 131072 (=[128][1024]).
__global__ __launch_bounds__(256) void gemm128_kernel(
    const float* __restrict__ A, const float* __restrict__ W,
    const float* __restrict__ bias, float* __restrict__ C, float* __restrict__ C1,
    int N, int K, int ldc, int kchunk, int aparts)
{
    __shared__ char Ab[128*64*2];
    __shared__ char Wb[64*64*2];
    const int t = threadIdx.x;
    const int wid = t >> 6, lane = t & 63;
    const int waveM = wid >> 1, waveN = wid & 1;
    const int lq = lane >> 4, lr = lane & 15;
    const int n0 = blockIdx.x * 64;
    const int kbeg = blockIdx.y * kchunk, kend = kbeg + kchunk;
    f32x4 acc[4][2];
#pragma unroll
    for (int i = 0; i < 4; ++i)
#pragma unroll
        for (int j = 0; j < 2; ++j) acc[i][j] = (f32x4){0.f,0.f,0.f,0.f};
    for (int kc = kbeg; kc < kend; kc += 64) {
        __syncthreads();
#pragma unroll
        for (int i = 0; i < 4; ++i) {
            int c = t + i*256;
            int row = c >> 3, k8 = (c & 7) << 3;
            const float* src = A + (size_t)row*K + kc + k8;
            float f[8];
            *(float4*)f     = *(const float4*)src;
            *(float4*)(f+4) = *(const float4*)(src+4);
            if (aparts == 4) {
#pragma unroll
                for (int p = 1; p < 4; ++p) {
                    float g0[8];
                    *(float4*)g0     = *(const float4*)(src + p*131072);
                    *(float4*)(g0+4) = *(const float4*)(src + p*131072 + 4);
#pragma unroll
                    for (int j = 0; j < 8; ++j) f[j] += g0[j];
                }
            }
            int byte = row*128 + ((k8*2) ^ ((row&7)<<4));
            *(bf16x8*)(Ab + byte) = pack8(f);
        }
#pragma unroll
        for (int i = 0; i < 2; ++i) {
            int c = t + i*256;
            int row = c >> 3, k8 = (c & 7) << 3;
            int n = n0 + row;
            float f[8] = {0,0,0,0,0,0,0,0};
            if (n < N) {
                const float* src = W + (size_t)n*K + kc + k8;
                *(float4*)f     = *(const float4*)src;
                *(float4*)(f+4) = *(const float4*)(src+4);
            }
            int byte = row*128 + ((k8*2) ^ ((row&7)<<4));
            *(bf16x8*)(Wb + byte) = pack8(f);
        }
        __syncthreads();
#pragma unroll
        for (int kf = 0; kf < 2; ++kf) {
            int kk2 = (kf*32 + (lq<<3)) * 2;
            bf16x8 bfr[2];
#pragma unroll
            for (int nf = 0; nf < 2; ++nf) {
                int r = waveN*32 + nf*16 + lr;
                bfr[nf] = *(const bf16x8*)(Wb + r*128 + (kk2 ^ ((r&7)<<4)));
            }
#pragma unroll
            for (int mf = 0; mf < 4; ++mf) {
                int r = waveM*64 + mf*16 + lr;
                bf16x8 afr = *(const bf16x8*)(Ab + r*128 + (kk2 ^ ((r&7)<<4)));
#pragma unroll
                for (int nf = 0; nf < 2; ++nf)
                    acc[mf][nf] = __builtin_amdgcn_mfma_f32_16x16x32_bf16(afr, bfr[nf], acc[mf][nf], 0, 0, 0);
            }
        }
    }
    float* Cp = (blockIdx.y == 0) ? C : (C1 + (size_t)(blockIdx.y - 1) * 128 * (size_t)ldc);
    bool addb = (bias != nullptr) && (blockIdx.y == 0);
#pragma unroll
    for (int mf = 0; mf < 4; ++mf)
#pragma unroll
        for (int nf = 0; nf < 2; ++nf) {
            int n = n0 + waveN*32 + nf*16 + lr;
            if (n < N) {
                float bv = addb ? bias[n] : 0.f;
#pragma unroll
                for (int r = 0; r < 4; ++r) {
                    int m = waveM*64 + mf*16 + (lq<<2) + r;
                    Cp[(size_t)m*ldc + n] = acc[mf][nf][r] + bv;
                }
            }
        }
}

// ---------------- GRU gates (reads 2-way K-split partials) ----------------
__global__ __launch_bounds__(256) void gru_gate_kernel(
    const float* __restrict__ gxp, const float* __restrict__ ghp,
    const float* __restrict__ h0, float* __restrict__ s_t)
{
    int i = blockIdx.x*256 + threadIdx.x;
    int b = i >> 10, h = i & 1023;
    const float* gx0 = gxp + (size_t)b*3072;
    const float* gx1 = gx0 + 393216;
    const float* gh0 = ghp + (size_t)b*3072;
    const float* gh1 = gh0 + 393216;
    float grx = gx0[h] + gx1[h],        grh = gh0[h] + gh1[h];
    float gzx = gx0[h+1024]+gx1[h+1024], gzh = gh0[h+1024]+gh1[h+1024];
    float gnx = gx0[h+2048]+gx1[h+2048], gnh = gh0[h+2048]+gh1[h+2048];
    float r = 1.f/(1.f+__expf(-(grx + grh)));
    float z = 1.f/(1.f+__expf(-(gzx + gzh)));
    float n = fast_tanh(gnx + r*gnh);
    s_t[i] = (1.f-z)*n + z*h0[i];
}

// ---------------- K6 (bf16): fused attention-score GEMM, m97 structure + T2 swizzle ----
// __launch_bounds__(256,4): (256,5) caps VGPR 64->48 -> acc spills (round-8: 632us).
__global__ __launch_bounds__(256,4) void attn_gemm_bf16_kernel(
    const unsigned short* __restrict__ encb,   // [65536,1024] bf16
    const unsigned short* __restrict__ whb,    // [1024,1024] bf16
    const float* __restrict__ ds_part,         // [4][B,H] dec_feat partials
    const float* __restrict__ coverage,
    const float* __restrict__ Wc, const float* __restrict__ Vv,
    float* __restrict__ e_part)                // [8][65536]
{
    __shared__ char Ab[128*128];   // [128 rows][64 bf16], source-pre-swizzled
    __shared__ char Bb[128*128];
    const int t = threadIdx.x;
    const int wid = t >> 6, lane = t & 63;
    const int waveM = wid >> 1, waveN = wid & 1;
    const int lq = lane >> 4, lr = lane & 15;
    int bid = blockIdx.x;
    int wg = (bid & 7) * 512 + (bid >> 3);
    const int nt = wg & 7, mt = wg >> 3;
    const int m0 = mt * 128, n0 = nt * 128;
    const int b = m0 >> 9;

    const int grow = wid*8 + (lane >> 3);
    const int gk16 = (lane & 7) ^ ((lane >> 3) & 7);  // pre-swizzled 16B unit (T2)
    const unsigned short* asrc = encb + (size_t)(m0 + grow)*H_ + gk16*8;
    const unsigned short* bsrc = whb  + (size_t)(n0 + grow)*H_ + gk16*8;
    char* aldst = Ab + wid*1024;
    char* bldst = Bb + wid*1024;

    f32x4 acc[4][4];
#pragma unroll
    for (int i = 0; i < 4; ++i)
#pragma unroll
        for (int j = 0; j < 4; ++j) acc[i][j] = (f32x4){0.f,0.f,0.f,0.f};

    for (int kc = 0; kc < 1024; kc += 64) {
        __syncthreads();
#pragma unroll
        for (int i = 0; i < 4; ++i) {
            gload16(asrc + kc + i*32*H_, aldst + i*4096);
            gload16(bsrc + kc + i*32*H_, bldst + i*4096);
        }
        __syncthreads();
#pragma unroll
        for (int kf = 0; kf < 2; ++kf) {
            const int koff = kf*64 + lq*16;
            bf16x8 bfr[4];
#pragma unroll
            for (int nf = 0; nf < 4; ++nf) {
                int r = waveN*64 + nf*16 + lr;
                bfr[nf] = *(const bf16x8*)(Bb + r*128 + (koff ^ ((r&7)<<4)));
            }
#pragma unroll
            for (int mf = 0; mf < 4; ++mf) {
                int r = waveM*64 + mf*16 + lr;
                bf16x8 afr = *(const bf16x8*)(Ab + r*128 + (koff ^ ((r&7)<<4)));
#pragma unroll
                for (int nf = 0; nf < 4; ++nf)
                    acc[mf][nf] = __builtin_amdgcn_mfma_f32_16x16x32_bf16(afr, bfr[nf], acc[mf][nf], 0, 0, 0);
            }
        }
    }
    float cv[4][4];
#pragma unroll
    for (int mf = 0; mf < 4; ++mf)
#pragma unroll
        for (int r = 0; r < 4; ++r) {
            int m = m0 + waveM*64 + mf*16 + lq*4 + r;
            cv[mf][r] = coverage[b*S_ + (m & 511)];
        }
    float e_acc[4][4] = {};
#pragma unroll
    for (int nf = 0; nf < 4; ++nf) {
        int n = n0 + waveN*64 + nf*16 + lr;
        const float* dsp = ds_part + b*H_ + n;
        float df = dsp[0] + dsp[131072] + dsp[262144] + dsp[393216];
        float wc = Wc[n];
        float vv = Vv[n];
#pragma unroll
        for (int mf = 0; mf < 4; ++mf)
#pragma unroll
            for (int r = 0; r < 4; ++r)
                e_acc[mf][r] += fast_tanh(acc[mf][nf][r] + df + cv[mf][r]*wc) * vv;
    }
#pragma unroll
    for (int msk = 1; msk < 16; msk <<= 1)
#pragma unroll
        for (int mf = 0; mf < 4; ++mf)
#pragma unroll
            for (int r = 0; r < 4; ++r)
                e_acc[mf][r] += __shfl_xor(e_acc[mf][r], msk);
    __syncthreads();
    float* el = (float*)Ab;          // epilogue buffer aliased into Ab
    if (lr == 0) {
#pragma unroll
        for (int mf = 0; mf < 4; ++mf)
#pragma unroll
            for (int r = 0; r < 4; ++r)
                el[waveN*128 + waveM*64 + mf*16 + lq*4 + r] = e_acc[mf][r];
    }
    __syncthreads();
    if (t < 128)
        e_part[(size_t)nt*65536 + m0 + t] = el[t] + el[128 + t];
}

// ---------------- K6 fallback (f32 staging) ----------------
__global__ __launch_bounds__(512,4) void attn_gemm_f32_kernel(
    const float* __restrict__ enc, const float* __restrict__ Wh,
    const float* __restrict__ ds_part, const float* __restrict__ coverage,
    const float* __restrict__ Wc, const float* __restrict__ Vv,
    float* __restrict__ e_part)
{
    __shared__ char Ab[128*64*2];
    __shared__ char Bb[256*64*2];
    __shared__ float e_lds[4][128];
    const int t = threadIdx.x;
    const int wid = t >> 6, lane = t & 63;
    const int waveM = wid >> 2, waveN = wid & 3;
    const int lq = lane >> 4, lr = lane & 15;
    int bid = blockIdx.x;
    int wg = (bid & 7) * 256 + (bid >> 3);
    const int mt = wg >> 2, nt = wg & 3;
    const int m0 = mt * 128, n0 = nt * 256;
    const int b = m0 >> 9;
    const int arow = t >> 2, ak0 = (t & 3) * 16;
    const int brow = t >> 1, bk0 = (t & 1) * 32;
    f32x4 acc[4][4];
#pragma unroll
    for (int i = 0; i < 4; ++i)
#pragma unroll
        for (int j = 0; j < 4; ++j) acc[i][j] = (f32x4){0.f,0.f,0.f,0.f};
    for (int kc = 0; kc < 1024; kc += 64) {
        __syncthreads();
        {
            const float* src = enc + (size_t)(m0 + arow)*H_ + kc + ak0;
            float f[16];
            *(float4*)(f)    = *(const float4*)(src);
            *(float4*)(f+4)  = *(const float4*)(src+4);
            *(float4*)(f+8)  = *(const float4*)(src+8);
            *(float4*)(f+12) = *(const float4*)(src+12);
            char* dst = Ab + arow*128;
            int sw = (arow & 7) << 4;
            *(bf16x8*)(dst + ((ak0*2)      ^ sw)) = pack8(f);
            *(bf16x8*)(dst + ((ak0*2 + 16) ^ sw)) = pack8(f+8);
        }
        {
            const float* src = Wh + (size_t)(n0 + brow)*H_ + kc + bk0;
            char* dst = Bb + brow*128;
            int sw = (brow & 7) << 4;
            float f[16];
            *(float4*)(f)    = *(const float4*)(src);
            *(float4*)(f+4)  = *(const float4*)(src+4);
            *(float4*)(f+8)  = *(const float4*)(src+8);
            *(float4*)(f+12) = *(const float4*)(src+12);
            *(bf16x8*)(dst + ((bk0*2)      ^ sw)) = pack8(f);
            *(bf16x8*)(dst + ((bk0*2 + 16) ^ sw)) = pack8(f+8);
            *(float4*)(f)    = *(const float4*)(src+16);
            *(float4*)(f+4)  = *(const float4*)(src+20);
            *(float4*)(f+8)  = *(const float4*)(src+24);
            *(float4*)(f+12) = *(const float4*)(src+28);
            *(bf16x8*)(dst + ((bk0*2 + 32) ^ sw)) = pack8(f);
            *(bf16x8*)(dst + ((bk0*2 + 48) ^ sw)) = pack8(f+8);
        }
        __syncthreads();
#pragma unroll
        for (int kf = 0; kf < 2; ++kf) {
            const int koff = kf*64 + lq*16;
            bf16x8 bfr[4];
#pragma unroll
            for (int nf = 0; nf < 4; ++nf) {
                int r = waveN*64 + nf*16 + lr;
                bfr[nf] = *(const bf16x8*)(Bb + r*128 + (koff ^ ((r&7)<<4)));
            }
#pragma unroll
            for (int mf = 0; mf < 4; ++mf) {
                int r = waveM*64 + mf*16 + lr;
                bf16x8 afr = *(const bf16x8*)(Ab + r*128 + (koff ^ ((r&7)<<4)));
#pragma unroll
                for (int nf = 0; nf < 4; ++nf)
                    acc[mf][nf] = __builtin_amdgcn_mfma_f32_16x16x32_bf16(afr, bfr[nf], acc[mf][nf], 0, 0, 0);
            }
        }
    }
    float cv[4][4];
#pragma unroll
    for (int mf = 0; mf < 4; ++mf)
#pragma unroll
        for (int r = 0; r < 4; ++r) {
            int m = m0 + waveM*64 + mf*16 + lq*4 + r;
            cv[mf][r] = coverage[b*S_ + (m & 511)];
        }
    float e_acc[4][4] = {};
#pragma unroll
    for (int nf = 0; nf < 4; ++nf) {
        int n = n0 + waveN*64 + nf*16 + lr;
        const float* dsp = ds_part + b*H_ + n;
        float df = dsp[0] + dsp[131072] + dsp[262144] + dsp[393216];
        float wc = Wc[n];
        float vv = Vv[n];
#pragma unroll
        for (int mf = 0; mf < 4; ++mf)
#pragma unroll
            for (int r = 0; r < 4; ++r)
                e_acc[mf][r] += fast_tanh(acc[mf][nf][r] + df + cv[mf][r]*wc) * vv;
    }
#pragma unroll
    for (int msk = 1; msk < 16; msk <<= 1)
#pragma unroll
        for (int mf = 0; mf < 4; ++mf)
#pragma unroll
            for (int r = 0; r < 4; ++r)
                e_acc[mf][r] += __shfl_xor(e_acc[mf][r], msk);
    if (lr == 0) {
#pragma unroll
        for (int mf = 0; mf < 4; ++mf)
#pragma unroll
            for (int r = 0; r < 4; ++r)
                e_lds[waveN][waveM*64 + mf*16 + lq*4 + r] = e_acc[mf][r];
    }
    __syncthreads();
    if (t < 128)
        e_part[(size_t)nt*65536 + m0 + t] = e_lds[0][t] + e_lds[1][t] + e_lds[2][t] + e_lds[3][t];
}

// ---------------- K7: softmax over S + coverage (sums np partials) ----------------
__global__ __launch_bounds__(256) void attn_softmax_kernel(
    const float* __restrict__ e_part, int np, const float* __restrict__ mask,
    const float* __restrict__ cov, float* __restrict__ att,
    float* __restrict__ cov_next, float* __restrict__ loss)
{
    __shared__ float red[256];
    int b = blockIdx.x, t = threadIdx.x;
    int i1 = b*S_ + t, i2 = i1 + 256;
    float e1 = mask[i1], e2 = mask[i2];
    for (int p = 0; p < np; ++p) { e1 += e_part[(size_t)p*65536 + i1]; e2 += e_part[(size_t)p*65536 + i2]; }
    red[t] = fmaxf(e1, e2); __syncthreads();
    for (int o = 128; o > 0; o >>= 1) { if (t < o) red[t] = fmaxf(red[t], red[t+o]); __syncthreads(); }
    float m = red[0]; __syncthreads();
    float a1 = __expf(e1-m), a2 = __expf(e2-m);
    red[t] = a1+a2; __syncthreads();
    for (int o = 128; o > 0; o >>= 1) { if (t < o) red[t] += red[t+o]; __syncthreads(); }
    float inv = 1.f/red[0]; __syncthreads();
    a1 *= inv; a2 *= inv;
    att[i1] = a1; att[i2] = a2;
    float c1 = cov[i1]+a1, c2 = cov[i2]+a2;
    cov_next[i1] = c1; cov_next[i2] = c2;
    red[t] = fminf(a1,c1)+fminf(a2,c2); __syncthreads();
    for (int o = 128; o > 0; o >>= 1) { if (t < o) red[t] += red[t+o]; __syncthreads(); }
    if (t == 0) loss[b] = red[0];
}

// ---------------- K8: h_t partials = att @ enc (bf16), vectorized 16B loads ----------
__global__ __launch_bounds__(256) void context_part_bf16_kernel(
    const float* __restrict__ att, const unsigned short* __restrict__ encb, float* __restrict__ hq)
{
    __shared__ float asl[128];
    __shared__ float cpart[128][9];   // +1 pad: avoid 8-stride bank conflicts
    int b = blockIdx.x, q = blockIdx.y, t = threadIdx.x;
    if (t < 128) asl[t] = att[b*S_ + q*128 + t];
    __syncthreads();
    int lane = t & 127, su = t >> 7;
    int hc = lane * 8;
    const unsigned short* ep = encb + ((size_t)(b*S_ + q*128 + su*64))*H_ + hc;
    float acc[8] = {};
#pragma unroll 2
    for (int s = 0; s < 64; ++s) {
        uint4 v = *(const uint4*)(ep + (size_t)s*H_);
        float w = asl[su*64 + s];
        const unsigned short* pv = (const unsigned short*)&v;
#pragma unroll
        for (int k = 0; k < 8; ++k) acc[k] += w * bf2f(pv[k]);
    }
    if (su == 1) {
#pragma unroll
        for (int k = 0; k < 8; ++k) cpart[lane][k] = acc[k];
    }
    __syncthreads();
    if (su == 0) {
        float o[8];
#pragma unroll
        for (int k = 0; k < 8; ++k) o[k] = acc[k] + cpart[lane][k];
        float* dst = hq + (size_t)q*131072 + (size_t)b*1024 + hc;
        *(float4*)dst     = *(float4*)o;
        *(float4*)(dst+4) = *(float4*)(o+4);
    }
}

__global__ __launch_bounds__(256) void context_part_f32_kernel(
    const float* __restrict__ att, const float* __restrict__ enc, float* __restrict__ hq)
{
    __shared__ float asl[128];
    int b = blockIdx.x, sub = blockIdx.y;
    int hh = sub & 1, q = sub >> 1;
    int t = threadIdx.x;
    if (t < 128) asl[t] = att[b*S_ + q*128 + t];
    __syncthreads();
    int h = hh*512 + t*2;
    const float* ep = enc + (size_t)b*S_*H_ + (size_t)q*128*H_ + h;
    float a0 = 0.f, a1 = 0.f;
#pragma unroll 4
    for (int s = 0; s < 128; ++s) {
        float2 v = *(const float2*)(ep + (size_t)s*H_);
        float w = asl[s];
        a0 += w*v.x; a1 += w*v.y;
    }
    float* o = hq + ((size_t)q*B_ + b)*H_ + h;
    o[0] = a0; o[1] = a1;
}

// ---------------- K9: fused hq-reduce + x_part-reduce + h_t + p_gen + A2 ----------------
__global__ __launch_bounds__(256) void pgen_kernel(
    const float* __restrict__ hq, const float* __restrict__ s_t, const float* __restrict__ x_part,
    const float* __restrict__ pgW, const float* __restrict__ pgb,
    float* __restrict__ pgen, float* __restrict__ h_t, float* __restrict__ A2)
{
    __shared__ float red[256];
    int b = blockIdx.x, t = threadIdx.x;
    float dot = 0.f;
#pragma unroll
    for (int i = 0; i < 4; ++i) {
        int j = t + i*256;
        const float* hp = hq + (size_t)b*1024 + j;
        float hv = hp[0] + hp[131072] + hp[262144] + hp[393216];
        const float* xp = x_part + (size_t)b*1024 + j;
        float xv = xp[0] + xp[131072] + xp[262144] + xp[393216];
        float sv = s_t[b*1024 + j];
        h_t[b*1024 + j] = hv;
        A2[(size_t)b*2048 + j] = sv;
        A2[(size_t)b*2048 + 1024 + j] = hv;
        dot += hv*pgW[j] + sv*pgW[1024+j] + xv*pgW[2048+j];
    }
    red[t] = dot; __syncthreads();
    for (int o = 128; o > 0; o >>= 1) { if (t < o) red[t] += red[t+o]; __syncthreads(); }
    if (t == 0) {
        float p = 1.f/(1.f+__expf(-(red[0] + pgb[0])));
        pgen[b] = fmaxf(p, EPS_);
    }
}

// ---------------- vocab pass 1: per-(row,chunk) online max/sum over (p0 [+ p1]) ------
__global__ __launch_bounds__(256) void vocab_pass1_kernel(
    const float* __restrict__ p0, const float* __restrict__ p1, int two,
    float2* __restrict__ mpart)
{
    __shared__ float rm[256], rl[256];
    int b = blockIdx.x, c = blockIdx.y, t = threadIdx.x;
    int lo = c * 12625;
    int hi = min(lo + 12625, V_);
    const float* row = p0 + (size_t)b*VE_;
    const float* row1 = two ? (p1 + (size_t)b*VE_) : row;
    float m = -1e30f, l = 0.f;
    for (int i = lo + t; i < hi; i += 256) {
        float v = row[i];
        if (two) v += row1[i];
        if (v > m) { l = l*__expf(m-v) + 1.f; m = v; }
        else l += __expf(v-m);
    }
    rm[t] = m; rl[t] = l; __syncthreads();
    for (int o = 128; o > 0; o >>= 1) {
        if (t < o) {
            float m1 = rm[t], m2 = rm[t+o];
            float M = fmaxf(m1, m2);
            rl[t] = rl[t]*__expf(m1-M) + rl[t+o]*__expf(m2-M);
            rm[t] = M;
        }
        __syncthreads();
    }
    if (t == 0) mpart[b*4 + c] = make_float2(rm[0], rl[0]);
}

// ---------------- vocab pass 2: prob + scatter(bitmap+hash) + clip + log, in place ----
__global__ __launch_bounds__(256) void vocab_pass2_kernel(
    const float* __restrict__ p0, const float* __restrict__ p1, int two,
    const float2* __restrict__ mpart,
    const float* __restrict__ pgen, const int* __restrict__ ebev,
    const float* __restrict__ att, float* __restrict__ out0)
{
    __shared__ unsigned bmap[395];     // ceil(12625/32)
    __shared__ unsigned hkey[1024];
    __shared__ float hval[1024];
    int b = blockIdx.x, c = blockIdx.y, t = threadIdx.x;
    int lo = c * 12625, hi = lo + 12625;
    float2 q0 = mpart[b*4+0], q1 = mpart[b*4+1], q2 = mpart[b*4+2], q3 = mpart[b*4+3];
    float M = fmaxf(fmaxf(q0.x, q1.x), fmaxf(q2.x, q3.x));
    float L = q0.y*__expf(q0.x-M) + q1.y*__expf(q1.x-M) + q2.y*__expf(q2.x-M) + q3.y*__expf(q3.x-M);
    float pg = pgen[b];
    float inv = pg / L;
    for (int i = t; i < 395; i += 256) bmap[i] = 0u;
    for (int i = t; i < 1024; i += 256) { hkey[i] = 0xFFFFFFFFu; hval[i] = 0.f; }
    __syncthreads();
    for (int s = t; s < 512; s += 256) {
        int col = ebev[b*S_ + s];
        if (col >= lo && col < hi) {
            float v = (1.f - pg) * att[b*S_ + s];
            unsigned cl = (unsigned)(col - lo);
            atomicOr(&bmap[cl >> 5], 1u << (cl & 31));
            unsigned slot = (cl * 2654435761u >> 16) & 1023u;
            while (true) {
                unsigned old = atomicCAS(&hkey[slot], 0xFFFFFFFFu, cl);
                if (old == 0xFFFFFFFFu || old == cl) { atomicAdd(&hval[slot], v); break; }
                slot = (slot + 1) & 1023u;
            }
        }
    }
    __syncthreads();
    const float* row = p0 + (size_t)b*VE_;
    const float* row1 = two ? (p1 + (size_t)b*VE_) : row;
    float* orow = out0 + (size_t)b*VE_;
    for (int i = lo + t; i < hi; i += 256) {
        float base = 0.f;
        if (i < V_) {
            float v = row[i];
            if (two) v += row1[i];
            base = __expf(v - M) * inv;
        }
        unsigned cl = (unsigned)(i - lo);
        if (bmap[cl >> 5] & (1u << (cl & 31))) {
            unsigned slot = (cl * 2654435761u >> 16) & 1023u;
            while (hkey[slot] != cl) slot = (slot + 1) & 1023u;
            base += hval[slot];
        }
        orow[i] = __logf(fmaxf(base, EPS_));
    }
}

extern "C" void kernel_launch(void* const* d_in, const int* in_sizes, int n_in,
                              void* d_out, int out_size, void* d_ws, size_t ws_size,
                              hipStream_t stream) {
    const int*   tok        = (const int*)d_in[0];
    const float* dec_hidden = (const float*)d_in[1];
    const float* enc        = (const float*)d_in[2];
    const float* mask       = (const float*)d_in[3];
    const float* ctx1       = (const float*)d_in[4];
    const int*   ebev       = (const int*)d_in[5];
    const float* cov        = (const float*)d_in[7];
    const float* embed      = (const float*)d_in[8];
    const float* ln_g       = (const float*)d_in[9];
    const float* ln_b       = (const float*)d_in[10];
    const float* xc_W       = (const float*)d_in[11];
    const float* xc_b       = (const float*)d_in[12];
    const float* W_ih       = (const float*)d_in[13];
    const float* W_hh       = (const float*)d_in[14];
    const float* b_ih       = (const float*)d_in[15];
    const float* b_hh       = (const float*)d_in[16];
    const float* Wh         = (const float*)d_in[17];
    const float* Ws         = (const float*)d_in[18];
    const float* Ws_b       = (const float*)d_in[19];
    const float* Wc         = (const float*)d_in[20];
    const float* Vv         = (const float*)d_in[21];
    const float* pg_W       = (const float*)d_in[22];
    const float* pg_b       = (const float*)d_in[23];
    const float* out1_W     = (const float*)d_in[24];
    const float* out1_b     = (const float*)d_in[25];
    const float* out2_W     = (const float*)d_in[26];
    const float* out2_b     = (const float*)d_in[27];

    float* out      = (float*)d_out;
    float* s_t      = out + 6464000;
    float* h_t      = out + 6595072;
    float* cov_next = out + 6726144;
    float* loss     = out + 6791680;

    const size_t ENC_SLOTS = 33554432, WH_SLOTS = 524288;
    const size_t BASE_MIN  = 5178496;                 // without logits split
    const size_t BASE_SPLIT = 5178496 + 6464000;      // + logit_p1
    const size_t need  = (ENC_SLOTS + WH_SLOTS + BASE_MIN) * 4;
    const size_t need2 = (ENC_SLOTS + WH_SLOTS + BASE_SPLIT) * 4;
    const bool bf16_path = (ws_size >= need);
    const bool split2 = bf16_path && (ws_size >= need2);

    float* wsf = (float*)d_ws;
    unsigned short* enc_bf = (unsigned short*)d_ws;
    unsigned short* wh_bf  = (unsigned short*)(wsf + ENC_SLOTS);
    float* base     = bf16_path ? (wsf + ENC_SLOTS + WH_SLOTS) : wsf;
    float* x_cat    = base;             // 262144
    float* x_part   = base + 262144;    // 4 x 131072 (ends 786432)
    float* gx_part  = base + 917504;    // 2 x 393216
    float* gh_part  = base + 1703936;   // 2 x 393216
    float* ds_part  = base + 2490368;   // 4 x 131072
    float* e_part   = base + 3145728;   // 8 x 65536
    float* att      = base + 3670016;   // 65536
    float* pgen     = base + 3735552;   // 128
    float* A2       = base + 3735680;   // 262144
    float* h2_part  = base + 3997824;   // 4 x 131072 (ends 4522112)
    float* hq       = base + 4653184;   // 4 x 131072 (ends 5177472)
    float2* mpart   = (float2*)(base + 5177472);  // 128 x 4 float2 (ends 5178496)
    float* logit_p1 = base + 5178496;   // 6464000 (split2 only)

    if (bf16_path) {
        cvt_bf16_kernel<<<32768, 256, 0, stream>>>(enc, enc_bf);
        cvt_bf16_kernel<<<512, 256, 0, stream>>>(Wh, wh_bf);
    }
    embed_ln_kernel<<<128, 256, 0, stream>>>(tok, embed, ln_g, ln_b, ctx1, x_cat);
    // xc: x_part = x_cat @ xc_W^T (4 K-slices, no reduce -- consumers sum)
    gemm128_kernel<<<dim3(16,4), 256, 0, stream>>>(x_cat, xc_W, xc_b, x_part, x_part + 131072, 1024, 2048, 1024, 512, 1);
    // gx: A = sum of 4 x_part slices (aparts=4)
    gemm128_kernel<<<dim3(48,2), 256, 0, stream>>>(x_part, W_ih, b_ih, gx_part, gx_part + 393216, 3072, 1024, 3072, 512, 4);
    gemm128_kernel<<<dim3(48,2), 256, 0, stream>>>(dec_hidden, W_hh, b_hh, gh_part, gh_part + 393216, 3072, 1024, 3072, 512, 1);
    gru_gate_kernel<<<512, 256, 0, stream>>>(gx_part, gh_part, dec_hidden, s_t);
    gemm128_kernel<<<dim3(16,4), 256, 0, stream>>>(s_t, Ws, Ws_b, ds_part, ds_part + 131072, 1024, 1024, 1024, 256, 1);

    int npart;
    if (bf16_path) {
        attn_gemm_bf16_kernel<<<4096, 256, 0, stream>>>(enc_bf, wh_bf, ds_part, cov, Wc, Vv, e_part);
        npart = 8;
    } else {
        attn_gemm_f32_kernel<<<2048, 512, 0, stream>>>(enc, Wh, ds_part, cov, Wc, Vv, e_part);
        npart = 4;
    }
    attn_softmax_kernel<<<128, 256, 0, stream>>>(e_part, npart, mask, cov, att, cov_next, loss);
    if (bf16_path) {
        dim3 g8(128, 4);
        context_part_bf16_kernel<<<g8, 256, 0, stream>>>(att, enc_bf, hq);
    } else {
        dim3 g8(128, 8);
        context_part_f32_kernel<<<g8, 256, 0, stream>>>(att, enc, hq);
    }
    pgen_kernel<<<128, 256, 0, stream>>>(hq, s_t, x_part, pg_W, pg_b, pgen, h_t, A2);
    // out1: h2_part = A2 @ out1_W^T (4 K-slices, no reduce -- logits sums via aparts)
    gemm128_kernel<<<dim3(16,4), 256, 0, stream>>>(A2, out1_W, out1_b, h2_part, h2_part + 131072, 1024, 2048, 1024, 512, 1);

    if (split2) {
        gemm128_kernel<<<dim3(782,2), 256, 0, stream>>>(h2_part, out2_W, out2_b, out, logit_p1, 50000, 1024, VE_, 512, 4);
        vocab_pass1_kernel<<<dim3(128,4), 256, 0, stream>>>(out, logit_p1, 1, mpart);
        vocab_pass2_kernel<<<dim3(128,4), 256, 0, stream>>>(out, logit_p1, 1, mpart, pgen, ebev, att, out);
    } else {
        gemm128_kernel<<<dim3(782,1), 256, 0, stream>>>(h2_part, out2_W, out2_b, out, nullptr, 50000, 1024, VE_, 1024, 4);
        vocab_pass1_kernel<<<dim3(128,4), 256, 0, stream>>>(out, nullptr, 0, mpart);
        vocab_pass2_kernel<<<dim3(128,4), 256, 0, stream>>>(out, nullptr, 0, mpart, pgen, ebev, att, out);
    }
}

// Round 11
// 491.699 us; speedup vs baseline: 1.1596x; 1.1596x over previous
//
#include <hip/hip_runtime.h>
#include <hip/hip_bf16.h>
#include <stdint.h>

#define B_ 128
#define S_ 512
#define H_ 1024
#define E_ 1024
#define V_ 50000
#define EXTRA_ 500
#define VE_ 50500
#define EPS_ 1e-8f

typedef __attribute__((ext_vector_type(4))) float f32x4;
typedef __attribute__((ext_vector_type(8))) short bf16x8;

__device__ __forceinline__ unsigned short f2bf(float f) {
    unsigned u = __builtin_bit_cast(unsigned, f);
    u = (u + 0x7FFFu + ((u >> 16) & 1u)) >> 16;
    return (unsigned short)u;
}

__device__ __forceinline__ bf16x8 pack8(const float* f) {
    union { bf16x8 v; unsigned short s[8]; } u;
#pragma unroll
    for (int i = 0; i < 8; ++i) u.s[i] = f2bf(f[i]);
    return u.v;
}

__device__ __forceinline__ float bf2f(unsigned short s) {
    unsigned u = (unsigned)s << 16;
    return __builtin_bit_cast(float, u);
}

__device__ __forceinline__ float fast_tanh(float x) {
    x = fminf(fmaxf(x, -15.f), 15.f);
    float e = __expf(2.f * x);
    return __fdividef(e - 1.f, e + 1.f);
}

// async global->LDS, 16 bytes per lane; lds dest is wave-uniform-base + lane*16
__device__ __forceinline__ void gload16(const void* g, void* l) {
    __builtin_amdgcn_global_load_lds(
        reinterpret_cast<const __attribute__((address_space(1))) unsigned int*>(
            reinterpret_cast<uintptr_t>(g)),
        reinterpret_cast<__attribute__((address_space(3))) unsigned int*>(
            reinterpret_cast<uintptr_t>(l)),
        16, 0, 0);
}

// ---------------- K0: f32 -> bf16 convert (Wh for blocks <512, enc after) ------------
__global__ __launch_bounds__(256) void cvt2_bf16_kernel(
    const float* __restrict__ enc, const float* __restrict__ wh,
    unsigned short* __restrict__ enc_bf, unsigned short* __restrict__ wh_bf)
{
    int bid = blockIdx.x;
    const float* in; unsigned short* out; int i;
    if (bid < 512) { in = wh;  out = wh_bf;  i = (bid * 256 + threadIdx.x) * 8; }
    else           { in = enc; out = enc_bf; i = ((bid - 512) * 256 + threadIdx.x) * 8; }
    float f[8];
    *(float4*)f     = *(const float4*)(in + i);
    *(float4*)(f+4) = *(const float4*)(in + i + 4);
    union { uint4 v; unsigned short s[8]; } u;
#pragma unroll
    for (int j = 0; j < 8; ++j) u.s[j] = f2bf(f[j]);
    *(uint4*)(out + i) = u.v;
}

// ---------------- K1: embedding + layernorm + concat ----------------
__global__ __launch_bounds__(256) void embed_ln_kernel(
    const int* __restrict__ tok, const float* __restrict__ embed,
    const float* __restrict__ g, const float* __restrict__ beta,
    const float* __restrict__ ctx, float* __restrict__ x_cat)
{
    __shared__ float red[256];
    int b = blockIdx.x, t = threadIdx.x;
    const float* row = embed + (size_t)tok[b] * E_;
    float v[4];
    float s = 0.f;
#pragma unroll
    for (int i = 0; i < 4; ++i) { v[i] = row[t + i*256]; s += v[i]; }
    red[t] = s; __syncthreads();
    for (int o = 128; o > 0; o >>= 1) { if (t < o) red[t] += red[t+o]; __syncthreads(); }
    float mu = red[0] * (1.f/E_);
    __syncthreads();
    s = 0.f;
#pragma unroll
    for (int i = 0; i < 4; ++i) { float d = v[i]-mu; s += d*d; }
    red[t] = s; __syncthreads();
    for (int o = 128; o > 0; o >>= 1) { if (t < o) red[t] += red[t+o]; __syncthreads(); }
    float inv = rsqrtf(red[0]*(1.f/E_) + 1e-5f);
    float* xrow = x_cat + (size_t)b * 2048;
#pragma unroll
    for (int i = 0; i < 4; ++i) {
        int j = t + i*256;
        xrow[j] = (v[i]-mu)*inv*g[j] + beta[j];
        xrow[1024 + j] = ctx[b*1024 + j];
    }
}

// ---------------- generic M=128 GEMM with K-split ----------------
// slice y writes to C + y*128*ldc; bias added only on slice 0.
__global__ __launch_bounds__(256) void gemm128_kernel(
    const float* __restrict__ A, const float* __restrict__ W,
    const float* __restrict__ bias, float* __restrict__ C,
    int N, int K, int ldc, int kchunk)
{
    __shared__ char Ab[128*64*2];
    __shared__ char Wb[64*64*2];
    const int t = threadIdx.x;
    const int wid = t >> 6, lane = t & 63;
    const int waveM = wid >> 1, waveN = wid & 1;
    const int lq = lane >> 4, lr = lane & 15;
    const int n0 = blockIdx.x * 64;
    const int kbeg = blockIdx.y * kchunk, kend = kbeg + kchunk;
    f32x4 acc[4][2];
#pragma unroll
    for (int i = 0; i < 4; ++i)
#pragma unroll
        for (int j = 0; j < 2; ++j) acc[i][j] = (f32x4){0.f,0.f,0.f,0.f};
    for (int kc = kbeg; kc < kend; kc += 64) {
        __syncthreads();
#pragma unroll
        for (int i = 0; i < 4; ++i) {
            int c = t + i*256;
            int row = c >> 3, k8 = (c & 7) << 3;
            const float* src = A + (size_t)row*K + kc + k8;
            float f[8];
            *(float4*)f     = *(const float4*)src;
            *(float4*)(f+4) = *(const float4*)(src+4);
            int byte = row*128 + ((k8*2) ^ ((row&7)<<4));
            *(bf16x8*)(Ab + byte) = pack8(f);
        }
#pragma unroll
        for (int i = 0; i < 2; ++i) {
            int c = t + i*256;
            int row = c >> 3, k8 = (c & 7) << 3;
            int n = n0 + row;
            float f[8] = {0,0,0,0,0,0,0,0};
            if (n < N) {
                const float* src = W + (size_t)n*K + kc + k8;
                *(float4*)f     = *(const float4*)src;
                *(float4*)(f+4) = *(const float4*)(src+4);
            }
            int byte = row*128 + ((k8*2) ^ ((row&7)<<4));
            *(bf16x8*)(Wb + byte) = pack8(f);
        }
        __syncthreads();
#pragma unroll
        for (int kf = 0; kf < 2; ++kf) {
            int kk2 = (kf*32 + (lq<<3)) * 2;
            bf16x8 bfr[2];
#pragma unroll
            for (int nf = 0; nf < 2; ++nf) {
                int r = waveN*32 + nf*16 + lr;
                bfr[nf] = *(const bf16x8*)(Wb + r*128 + (kk2 ^ ((r&7)<<4)));
            }
#pragma unroll
            for (int mf = 0; mf < 4; ++mf) {
                int r = waveM*64 + mf*16 + lr;
                bf16x8 afr = *(const bf16x8*)(Ab + r*128 + (kk2 ^ ((r&7)<<4)));
#pragma unroll
                for (int nf = 0; nf < 2; ++nf)
                    acc[mf][nf] = __builtin_amdgcn_mfma_f32_16x16x32_bf16(afr, bfr[nf], acc[mf][nf], 0, 0, 0);
            }
        }
    }
    float* Cp = C + (size_t)blockIdx.y * 128 * (size_t)ldc;
    bool addb = (bias != nullptr) && (blockIdx.y == 0);
#pragma unroll
    for (int mf = 0; mf < 4; ++mf)
#pragma unroll
        for (int nf = 0; nf < 2; ++nf) {
            int n = n0 + waveN*32 + nf*16 + lr;
            if (n < N) {
                float bv = addb ? bias[n] : 0.f;
#pragma unroll
                for (int r = 0; r < 4; ++r) {
                    int m = waveM*64 + mf*16 + (lq<<2) + r;
                    Cp[(size_t)m*ldc + n] = acc[mf][nf][r] + bv;
                }
            }
        }
}

// ---------------- dual GEMM: two independent same-shape problems in one dispatch ------
// blockIdx.z selects {A,W,bias,C}. Used for gx (x@W_ih^T) || gh (h0@W_hh^T).
__global__ __launch_bounds__(256) void gemm128_dual_kernel(
    const float* __restrict__ A0, const float* __restrict__ W0,
    const float* __restrict__ b0, float* __restrict__ C0,
    const float* __restrict__ A1, const float* __restrict__ W1,
    const float* __restrict__ b1, float* __restrict__ C1,
    int N, int K, int ldc, int kchunk)
{
    __shared__ char Ab[128*64*2];
    __shared__ char Wb[64*64*2];
    const float* A = blockIdx.z ? A1 : A0;
    const float* W = blockIdx.z ? W1 : W0;
    const float* bias = blockIdx.z ? b1 : b0;
    float* C = blockIdx.z ? C1 : C0;
    const int t = threadIdx.x;
    const int wid = t >> 6, lane = t & 63;
    const int waveM = wid >> 1, waveN = wid & 1;
    const int lq = lane >> 4, lr = lane & 15;
    const int n0 = blockIdx.x * 64;
    const int kbeg = blockIdx.y * kchunk, kend = kbeg + kchunk;
    f32x4 acc[4][2];
#pragma unroll
    for (int i = 0; i < 4; ++i)
#pragma unroll
        for (int j = 0; j < 2; ++j) acc[i][j] = (f32x4){0.f,0.f,0.f,0.f};
    for (int kc = kbeg; kc < kend; kc += 64) {
        __syncthreads();
#pragma unroll
        for (int i = 0; i < 4; ++i) {
            int c = t + i*256;
            int row = c >> 3, k8 = (c & 7) << 3;
            const float* src = A + (size_t)row*K + kc + k8;
            float f[8];
            *(float4*)f     = *(const float4*)src;
            *(float4*)(f+4) = *(const float4*)(src+4);
            int byte = row*128 + ((k8*2) ^ ((row&7)<<4));
            *(bf16x8*)(Ab + byte) = pack8(f);
        }
#pragma unroll
        for (int i = 0; i < 2; ++i) {
            int c = t + i*256;
            int row = c >> 3, k8 = (c & 7) << 3;
            int n = n0 + row;
            float f[8] = {0,0,0,0,0,0,0,0};
            if (n < N) {
                const float* src = W + (size_t)n*K + kc + k8;
                *(float4*)f     = *(const float4*)src;
                *(float4*)(f+4) = *(const float4*)(src+4);
            }
            int byte = row*128 + ((k8*2) ^ ((row&7)<<4));
            *(bf16x8*)(Wb + byte) = pack8(f);
        }
        __syncthreads();
#pragma unroll
        for (int kf = 0; kf < 2; ++kf) {
            int kk2 = (kf*32 + (lq<<3)) * 2;
            bf16x8 bfr[2];
#pragma unroll
            for (int nf = 0; nf < 2; ++nf) {
                int r = waveN*32 + nf*16 + lr;
                bfr[nf] = *(const bf16x8*)(Wb + r*128 + (kk2 ^ ((r&7)<<4)));
            }
#pragma unroll
            for (int mf = 0; mf < 4; ++mf) {
                int r = waveM*64 + mf*16 + lr;
                bf16x8 afr = *(const bf16x8*)(Ab + r*128 + (kk2 ^ ((r&7)<<4)));
#pragma unroll
                for (int nf = 0; nf < 2; ++nf)
                    acc[mf][nf] = __builtin_amdgcn_mfma_f32_16x16x32_bf16(afr, bfr[nf], acc[mf][nf], 0, 0, 0);
            }
        }
    }
    float* Cp = C + (size_t)blockIdx.y * 128 * (size_t)ldc;
    bool addb = (bias != nullptr) && (blockIdx.y == 0);
#pragma unroll
    for (int mf = 0; mf < 4; ++mf)
#pragma unroll
        for (int nf = 0; nf < 2; ++nf) {
            int n = n0 + waveN*32 + nf*16 + lr;
            if (n < N) {
                float bv = addb ? bias[n] : 0.f;
#pragma unroll
                for (int r = 0; r < 4; ++r) {
                    int m = waveM*64 + mf*16 + (lq<<2) + r;
                    Cp[(size_t)m*ldc + n] = acc[mf][nf][r] + bv;
                }
            }
        }
}

// ---------------- reduce 4 partial slices ----------------
__global__ __launch_bounds__(256) void reduce4_kernel(
    const float* __restrict__ in, float* __restrict__ out, int len)
{
    int i = blockIdx.x*256 + threadIdx.x;
    if (i < len) out[i] = in[i] + in[len+i] + in[2*len+i] + in[3*len+i];
}

// ---------------- GRU gates (reads 2-way K-split partials) ----------------
__global__ __launch_bounds__(256) void gru_gate_kernel(
    const float* __restrict__ gxp, const float* __restrict__ ghp,
    const float* __restrict__ h0, float* __restrict__ s_t)
{
    int i = blockIdx.x*256 + threadIdx.x;
    int b = i >> 10, h = i & 1023;
    const float* gx0 = gxp + (size_t)b*3072;
    const float* gx1 = gx0 + 393216;
    const float* gh0 = ghp + (size_t)b*3072;
    const float* gh1 = gh0 + 393216;
    float grx = gx0[h] + gx1[h],        grh = gh0[h] + gh1[h];
    float gzx = gx0[h+1024]+gx1[h+1024], gzh = gh0[h+1024]+gh1[h+1024];
    float gnx = gx0[h+2048]+gx1[h+2048], gnh = gh0[h+2048]+gh1[h+2048];
    float r = 1.f/(1.f+__expf(-(grx + grh)));
    float z = 1.f/(1.f+__expf(-(gzx + gzh)));
    float n = fast_tanh(gnx + r*gnh);
    s_t[i] = (1.f-z)*n + z*h0[i];
}

// ---------------- K6 (bf16): fused attention-score GEMM, m97 structure + T2 swizzle ----
// __launch_bounds__(256,4): (256,5) caps VGPR 64->48 -> acc spills (round-8: 632us).
__global__ __launch_bounds__(256,4) void attn_gemm_bf16_kernel(
    const unsigned short* __restrict__ encb,   // [65536,1024] bf16
    const unsigned short* __restrict__ whb,    // [1024,1024] bf16
    const float* __restrict__ ds_part,         // [4][B,H] dec_feat partials
    const float* __restrict__ coverage,
    const float* __restrict__ Wc, const float* __restrict__ Vv,
    float* __restrict__ e_part)                // [8][65536]
{
    __shared__ char Ab[128*128];   // [128 rows][64 bf16], source-pre-swizzled
    __shared__ char Bb[128*128];
    const int t = threadIdx.x;
    const int wid = t >> 6, lane = t & 63;
    const int waveM = wid >> 1, waveN = wid & 1;
    const int lq = lane >> 4, lr = lane & 15;
    int bid = blockIdx.x;
    int wg = (bid & 7) * 512 + (bid >> 3);
    const int nt = wg & 7, mt = wg >> 3;
    const int m0 = mt * 128, n0 = nt * 128;
    const int b = m0 >> 9;

    const int grow = wid*8 + (lane >> 3);
    const int gk16 = (lane & 7) ^ ((lane >> 3) & 7);  // pre-swizzled 16B unit (T2)
    const unsigned short* asrc = encb + (size_t)(m0 + grow)*H_ + gk16*8;
    const unsigned short* bsrc = whb  + (size_t)(n0 + grow)*H_ + gk16*8;
    char* aldst = Ab + wid*1024;
    char* bldst = Bb + wid*1024;

    f32x4 acc[4][4];
#pragma unroll
    for (int i = 0; i < 4; ++i)
#pragma unroll
        for (int j = 0; j < 4; ++j) acc[i][j] = (f32x4){0.f,0.f,0.f,0.f};

    for (int kc = 0; kc < 1024; kc += 64) {
        __syncthreads();
#pragma unroll
        for (int i = 0; i < 4; ++i) {
            gload16(asrc + kc + i*32*H_, aldst + i*4096);
            gload16(bsrc + kc + i*32*H_, bldst + i*4096);
        }
        __syncthreads();
#pragma unroll
        for (int kf = 0; kf < 2; ++kf) {
            const int koff = kf*64 + lq*16;
            bf16x8 bfr[4];
#pragma unroll
            for (int nf = 0; nf < 4; ++nf) {
                int r = waveN*64 + nf*16 + lr;
                bfr[nf] = *(const bf16x8*)(Bb + r*128 + (koff ^ ((r&7)<<4)));
            }
#pragma unroll
            for (int mf = 0; mf < 4; ++mf) {
                int r = waveM*64 + mf*16 + lr;
                bf16x8 afr = *(const bf16x8*)(Ab + r*128 + (koff ^ ((r&7)<<4)));
#pragma unroll
                for (int nf = 0; nf < 4; ++nf)
                    acc[mf][nf] = __builtin_amdgcn_mfma_f32_16x16x32_bf16(afr, bfr[nf], acc[mf][nf], 0, 0, 0);
            }
        }
    }
    float cv[4][4];
#pragma unroll
    for (int mf = 0; mf < 4; ++mf)
#pragma unroll
        for (int r = 0; r < 4; ++r) {
            int m = m0 + waveM*64 + mf*16 + lq*4 + r;
            cv[mf][r] = coverage[b*S_ + (m & 511)];
        }
    float e_acc[4][4] = {};
#pragma unroll
    for (int nf = 0; nf < 4; ++nf) {
        int n = n0 + waveN*64 + nf*16 + lr;
        const float* dsp = ds_part + b*H_ + n;
        float df = dsp[0] + dsp[131072] + dsp[262144] + dsp[393216];
        float wc = Wc[n];
        float vv = Vv[n];
#pragma unroll
        for (int mf = 0; mf < 4; ++mf)
#pragma unroll
            for (int r = 0; r < 4; ++r)
                e_acc[mf][r] += fast_tanh(acc[mf][nf][r] + df + cv[mf][r]*wc) * vv;
    }
#pragma unroll
    for (int msk = 1; msk < 16; msk <<= 1)
#pragma unroll
        for (int mf = 0; mf < 4; ++mf)
#pragma unroll
            for (int r = 0; r < 4; ++r)
                e_acc[mf][r] += __shfl_xor(e_acc[mf][r], msk);
    __syncthreads();
    float* el = (float*)Ab;          // epilogue buffer aliased into Ab
    if (lr == 0) {
#pragma unroll
        for (int mf = 0; mf < 4; ++mf)
#pragma unroll
            for (int r = 0; r < 4; ++r)
                el[waveN*128 + waveM*64 + mf*16 + lq*4 + r] = e_acc[mf][r];
    }
    __syncthreads();
    if (t < 128)
        e_part[(size_t)nt*65536 + m0 + t] = el[t] + el[128 + t];
}

// ---------------- K6 fallback (f32 staging) ----------------
__global__ __launch_bounds__(512,4) void attn_gemm_f32_kernel(
    const float* __restrict__ enc, const float* __restrict__ Wh,
    const float* __restrict__ ds_part, const float* __restrict__ coverage,
    const float* __restrict__ Wc, const float* __restrict__ Vv,
    float* __restrict__ e_part)
{
    __shared__ char Ab[128*64*2];
    __shared__ char Bb[256*64*2];
    __shared__ float e_lds[4][128];
    const int t = threadIdx.x;
    const int wid = t >> 6, lane = t & 63;
    const int waveM = wid >> 2, waveN = wid & 3;
    const int lq = lane >> 4, lr = lane & 15;
    int bid = blockIdx.x;
    int wg = (bid & 7) * 256 + (bid >> 3);
    const int mt = wg >> 2, nt = wg & 3;
    const int m0 = mt * 128, n0 = nt * 256;
    const int b = m0 >> 9;
    const int arow = t >> 2, ak0 = (t & 3) * 16;
    const int brow = t >> 1, bk0 = (t & 1) * 32;
    f32x4 acc[4][4];
#pragma unroll
    for (int i = 0; i < 4; ++i)
#pragma unroll
        for (int j = 0; j < 4; ++j) acc[i][j] = (f32x4){0.f,0.f,0.f,0.f};
    for (int kc = 0; kc < 1024; kc += 64) {
        __syncthreads();
        {
            const float* src = enc + (size_t)(m0 + arow)*H_ + kc + ak0;
            float f[16];
            *(float4*)(f)    = *(const float4*)(src);
            *(float4*)(f+4)  = *(const float4*)(src+4);
            *(float4*)(f+8)  = *(const float4*)(src+8);
            *(float4*)(f+12) = *(const float4*)(src+12);
            char* dst = Ab + arow*128;
            int sw = (arow & 7) << 4;
            *(bf16x8*)(dst + ((ak0*2)      ^ sw)) = pack8(f);
            *(bf16x8*)(dst + ((ak0*2 + 16) ^ sw)) = pack8(f+8);
        }
        {
            const float* src = Wh + (size_t)(n0 + brow)*H_ + kc + bk0;
            char* dst = Bb + brow*128;
            int sw = (brow & 7) << 4;
            float f[16];
            *(float4*)(f)    = *(const float4*)(src);
            *(float4*)(f+4)  = *(const float4*)(src+4);
            *(float4*)(f+8)  = *(const float4*)(src+8);
            *(float4*)(f+12) = *(const float4*)(src+12);
            *(bf16x8*)(dst + ((bk0*2)      ^ sw)) = pack8(f);
            *(bf16x8*)(dst + ((bk0*2 + 16) ^ sw)) = pack8(f+8);
            *(float4*)(f)    = *(const float4*)(src+16);
            *(float4*)(f+4)  = *(const float4*)(src+20);
            *(float4*)(f+8)  = *(const float4*)(src+24);
            *(float4*)(f+12) = *(const float4*)(src+28);
            *(bf16x8*)(dst + ((bk0*2 + 32) ^ sw)) = pack8(f);
            *(bf16x8*)(dst + ((bk0*2 + 48) ^ sw)) = pack8(f+8);
        }
        __syncthreads();
#pragma unroll
        for (int kf = 0; kf < 2; ++kf) {
            const int koff = kf*64 + lq*16;
            bf16x8 bfr[4];
#pragma unroll
            for (int nf = 0; nf < 4; ++nf) {
                int r = waveN*64 + nf*16 + lr;
                bfr[nf] = *(const bf16x8*)(Bb + r*128 + (koff ^ ((r&7)<<4)));
            }
#pragma unroll
            for (int mf = 0; mf < 4; ++mf) {
                int r = waveM*64 + mf*16 + lr;
                bf16x8 afr = *(const bf16x8*)(Ab + r*128 + (koff ^ ((r&7)<<4)));
#pragma unroll
                for (int nf = 0; nf < 4; ++nf)
                    acc[mf][nf] = __builtin_amdgcn_mfma_f32_16x16x32_bf16(afr, bfr[nf], acc[mf][nf], 0, 0, 0);
            }
        }
    }
    float cv[4][4];
#pragma unroll
    for (int mf = 0; mf < 4; ++mf)
#pragma unroll
        for (int r = 0; r < 4; ++r) {
            int m = m0 + waveM*64 + mf*16 + lq*4 + r;
            cv[mf][r] = coverage[b*S_ + (m & 511)];
        }
    float e_acc[4][4] = {};
#pragma unroll
    for (int nf = 0; nf < 4; ++nf) {
        int n = n0 + waveN*64 + nf*16 + lr;
        const float* dsp = ds_part + b*H_ + n;
        float df = dsp[0] + dsp[131072] + dsp[262144] + dsp[393216];
        float wc = Wc[n];
        float vv = Vv[n];
#pragma unroll
        for (int mf = 0; mf < 4; ++mf)
#pragma unroll
            for (int r = 0; r < 4; ++r)
                e_acc[mf][r] += fast_tanh(acc[mf][nf][r] + df + cv[mf][r]*wc) * vv;
    }
#pragma unroll
    for (int msk = 1; msk < 16; msk <<= 1)
#pragma unroll
        for (int mf = 0; mf < 4; ++mf)
#pragma unroll
            for (int r = 0; r < 4; ++r)
                e_acc[mf][r] += __shfl_xor(e_acc[mf][r], msk);
    if (lr == 0) {
#pragma unroll
        for (int mf = 0; mf < 4; ++mf)
#pragma unroll
            for (int r = 0; r < 4; ++r)
                e_lds[waveN][waveM*64 + mf*16 + lq*4 + r] = e_acc[mf][r];
    }
    __syncthreads();
    if (t < 128)
        e_part[(size_t)nt*65536 + m0 + t] = e_lds[0][t] + e_lds[1][t] + e_lds[2][t] + e_lds[3][t];
}

// ---------------- K7: softmax over S + coverage (sums np partials) ----------------
// (used by f32 fallback path; bf16 path fuses softmax into context below)
__global__ __launch_bounds__(256) void attn_softmax_kernel(
    const float* __restrict__ e_part, int np, const float* __restrict__ mask,
    const float* __restrict__ cov, float* __restrict__ att,
    float* __restrict__ cov_next, float* __restrict__ loss)
{
    __shared__ float red[256];
    int b = blockIdx.x, t = threadIdx.x;
    int i1 = b*S_ + t, i2 = i1 + 256;
    float e1 = mask[i1], e2 = mask[i2];
    for (int p = 0; p < np; ++p) { e1 += e_part[(size_t)p*65536 + i1]; e2 += e_part[(size_t)p*65536 + i2]; }
    red[t] = fmaxf(e1, e2); __syncthreads();
    for (int o = 128; o > 0; o >>= 1) { if (t < o) red[t] = fmaxf(red[t], red[t+o]); __syncthreads(); }
    float m = red[0]; __syncthreads();
    float a1 = __expf(e1-m), a2 = __expf(e2-m);
    red[t] = a1+a2; __syncthreads();
    for (int o = 128; o > 0; o >>= 1) { if (t < o) red[t] += red[t+o]; __syncthreads(); }
    float inv = 1.f/red[0]; __syncthreads();
    a1 *= inv; a2 *= inv;
    att[i1] = a1; att[i2] = a2;
    float c1 = cov[i1]+a1, c2 = cov[i2]+a2;
    cov_next[i1] = c1; cov_next[i2] = c2;
    red[t] = fminf(a1,c1)+fminf(a2,c2); __syncthreads();
    for (int o = 128; o > 0; o >>= 1) { if (t < o) red[t] += red[t+o]; __syncthreads(); }
    if (t == 0) loss[b] = red[0];
}

// ---------------- K7+K8 fused (bf16): softmax (recomputed per q-block) + context ------
// grid (128, 4) x 256 thr. Each block recomputes row-b softmax from e_part (L2-resident,
// ~16KB) -> removes the separate softmax launch; block q==0 writes att/cov_next/loss.
__global__ __launch_bounds__(256) void smax_ctx_bf16_kernel(
    const float* __restrict__ e_part, const float* __restrict__ mask,
    const float* __restrict__ cov, const unsigned short* __restrict__ encb,
    float* __restrict__ att, float* __restrict__ cov_next, float* __restrict__ loss,
    float* __restrict__ hq)
{
    __shared__ float red[256];
    __shared__ float asl[512];
    __shared__ float cpart[128][9];
    int b = blockIdx.x, q = blockIdx.y, t = threadIdx.x;
    int i1 = b*S_ + t, i2 = i1 + 256;
    float e1 = mask[i1], e2 = mask[i2];
#pragma unroll
    for (int p = 0; p < 8; ++p) { e1 += e_part[(size_t)p*65536 + i1]; e2 += e_part[(size_t)p*65536 + i2]; }
    red[t] = fmaxf(e1, e2); __syncthreads();
    for (int o = 128; o > 0; o >>= 1) { if (t < o) red[t] = fmaxf(red[t], red[t+o]); __syncthreads(); }
    float m = red[0]; __syncthreads();
    float a1 = __expf(e1-m), a2 = __expf(e2-m);
    red[t] = a1+a2; __syncthreads();
    for (int o = 128; o > 0; o >>= 1) { if (t < o) red[t] += red[t+o]; __syncthreads(); }
    float inv = 1.f/red[0]; __syncthreads();
    a1 *= inv; a2 *= inv;
    asl[t] = a1; asl[t+256] = a2;
    if (q == 0) {
        att[i1] = a1; att[i2] = a2;
        float c1 = cov[i1]+a1, c2 = cov[i2]+a2;
        cov_next[i1] = c1; cov_next[i2] = c2;
        red[t] = fminf(a1,c1)+fminf(a2,c2); __syncthreads();
        for (int o = 128; o > 0; o >>= 1) { if (t < o) red[t] += red[t+o]; __syncthreads(); }
        if (t == 0) loss[b] = red[0];
    }
    __syncthreads();
    // context chunk q: rows s in [q*128, q*128+128)
    int lane = t & 127, su = t >> 7;
    int hc = lane * 8;
    const unsigned short* ep = encb + ((size_t)(b*S_ + q*128 + su*64))*H_ + hc;
    const float* aw = asl + q*128 + su*64;
    float acc[8] = {};
#pragma unroll 2
    for (int s = 0; s < 64; ++s) {
        uint4 v = *(const uint4*)(ep + (size_t)s*H_);
        float w = aw[s];
        const unsigned short* pv = (const unsigned short*)&v;
#pragma unroll
        for (int k = 0; k < 8; ++k) acc[k] += w * bf2f(pv[k]);
    }
    if (su == 1) {
#pragma unroll
        for (int k = 0; k < 8; ++k) cpart[lane][k] = acc[k];
    }
    __syncthreads();
    if (su == 0) {
        float o[8];
#pragma unroll
        for (int k = 0; k < 8; ++k) o[k] = acc[k] + cpart[lane][k];
        float* dst = hq + (size_t)q*131072 + (size_t)b*1024 + hc;
        *(float4*)dst     = *(float4*)o;
        *(float4*)(dst+4) = *(float4*)(o+4);
    }
}

__global__ __launch_bounds__(256) void context_part_f32_kernel(
    const float* __restrict__ att, const float* __restrict__ enc, float* __restrict__ hq)
{
    __shared__ float asl[128];
    int b = blockIdx.x, sub = blockIdx.y;
    int hh = sub & 1, q = sub >> 1;
    int t = threadIdx.x;
    if (t < 128) asl[t] = att[b*S_ + q*128 + t];
    __syncthreads();
    int h = hh*512 + t*2;
    const float* ep = enc + (size_t)b*S_*H_ + (size_t)q*128*H_ + h;
    float a0 = 0.f, a1 = 0.f;
#pragma unroll 4
    for (int s = 0; s < 128; ++s) {
        float2 v = *(const float2*)(ep + (size_t)s*H_);
        float w = asl[s];
        a0 += w*v.x; a1 += w*v.y;
    }
    float* o = hq + ((size_t)q*B_ + b)*H_ + h;
    o[0] = a0; o[1] = a1;
}

// ---------------- K9: fused hq-reduce + h_t + p_gen + A2=[s_t,h_t] ----------------
__global__ __launch_bounds__(256) void pgen_kernel(
    const float* __restrict__ hq, const float* __restrict__ s_t, const float* __restrict__ x,
    const float* __restrict__ pgW, const float* __restrict__ pgb,
    float* __restrict__ pgen, float* __restrict__ h_t, float* __restrict__ A2)
{
    __shared__ float red[256];
    int b = blockIdx.x, t = threadIdx.x;
    float dot = 0.f;
#pragma unroll
    for (int i = 0; i < 4; ++i) {
        int j = t + i*256;
        const float* hp = hq + (size_t)b*1024 + j;
        float hv = hp[0] + hp[131072] + hp[262144] + hp[393216];
        float sv = s_t[b*1024 + j];
        h_t[b*1024 + j] = hv;
        A2[(size_t)b*2048 + j] = sv;
        A2[(size_t)b*2048 + 1024 + j] = hv;
        dot += hv*pgW[j] + sv*pgW[1024+j] + x[b*1024+j]*pgW[2048+j];
    }
    red[t] = dot; __syncthreads();
    for (int o = 128; o > 0; o >>= 1) { if (t < o) red[t] += red[t+o]; __syncthreads(); }
    if (t == 0) {
        float p = 1.f/(1.f+__expf(-(red[0] + pgb[0])));
        pgen[b] = fmaxf(p, EPS_);
    }
}

// ---------------- vocab pass 1: per-(row,chunk) online max/sum ----------------
__global__ __launch_bounds__(256) void vocab_pass1_kernel(
    const float* __restrict__ logits, float2* __restrict__ mpart)
{
    __shared__ float rm[256], rl[256];
    int b = blockIdx.x, c = blockIdx.y, t = threadIdx.x;
    int lo = c * 12625;
    int hi = min(lo + 12625, V_);
    const float* row = logits + (size_t)b*VE_;
    float m = -1e30f, l = 0.f;
    for (int i = lo + t; i < hi; i += 256) {
        float v = row[i];
        if (v > m) { l = l*__expf(m-v) + 1.f; m = v; }
        else l += __expf(v-m);
    }
    rm[t] = m; rl[t] = l; __syncthreads();
    for (int o = 128; o > 0; o >>= 1) {
        if (t < o) {
            float m1 = rm[t], m2 = rm[t+o];
            float M = fmaxf(m1, m2);
            rl[t] = rl[t]*__expf(m1-M) + rl[t+o]*__expf(m2-M);
            rm[t] = M;
        }
        __syncthreads();
    }
    if (t == 0) mpart[b*4 + c] = make_float2(rm[0], rl[0]);
}

// ---------------- vocab pass 2: prob + scatter(bitmap+hash) + clip + log, in place ----
__global__ __launch_bounds__(256) void vocab_pass2_kernel(
    const float* __restrict__ logits, const float2* __restrict__ mpart,
    const float* __restrict__ pgen, const int* __restrict__ ebev,
    const float* __restrict__ att, float* __restrict__ out0)
{
    __shared__ unsigned bmap[395];     // ceil(12625/32)
    __shared__ unsigned hkey[1024];
    __shared__ float hval[1024];
    int b = blockIdx.x, c = blockIdx.y, t = threadIdx.x;
    int lo = c * 12625, hi = lo + 12625;
    float2 p0 = mpart[b*4+0], p1 = mpart[b*4+1], p2 = mpart[b*4+2], p3 = mpart[b*4+3];
    float M = fmaxf(fmaxf(p0.x, p1.x), fmaxf(p2.x, p3.x));
    float L = p0.y*__expf(p0.x-M) + p1.y*__expf(p1.x-M) + p2.y*__expf(p2.x-M) + p3.y*__expf(p3.x-M);
    float pg = pgen[b];
    float inv = pg / L;
    for (int i = t; i < 395; i += 256) bmap[i] = 0u;
    for (int i = t; i < 1024; i += 256) { hkey[i] = 0xFFFFFFFFu; hval[i] = 0.f; }
    __syncthreads();
    for (int s = t; s < 512; s += 256) {
        int col = ebev[b*S_ + s];
        if (col >= lo && col < hi) {
            float v = (1.f - pg) * att[b*S_ + s];
            unsigned cl = (unsigned)(col - lo);
            atomicOr(&bmap[cl >> 5], 1u << (cl & 31));
            unsigned slot = (cl * 2654435761u >> 16) & 1023u;
            while (true) {
                unsigned old = atomicCAS(&hkey[slot], 0xFFFFFFFFu, cl);
                if (old == 0xFFFFFFFFu || old == cl) { atomicAdd(&hval[slot], v); break; }
                slot = (slot + 1) & 1023u;
            }
        }
    }
    __syncthreads();
    const float* row = logits + (size_t)b*VE_;
    float* orow = out0 + (size_t)b*VE_;
    for (int i = lo + t; i < hi; i += 256) {
        float base = 0.f;
        if (i < V_) base = __expf(row[i] - M) * inv;
        unsigned cl = (unsigned)(i - lo);
        if (bmap[cl >> 5] & (1u << (cl & 31))) {
            unsigned slot = (cl * 2654435761u >> 16) & 1023u;
            while (hkey[slot] != cl) slot = (slot + 1) & 1023u;
            base += hval[slot];
        }
        orow[i] = __logf(fmaxf(base, EPS_));
    }
}

extern "C" void kernel_launch(void* const* d_in, const int* in_sizes, int n_in,
                              void* d_out, int out_size, void* d_ws, size_t ws_size,
                              hipStream_t stream) {
    const int*   tok        = (const int*)d_in[0];
    const float* dec_hidden = (const float*)d_in[1];
    const float* enc        = (const float*)d_in[2];
    const float* mask       = (const float*)d_in[3];
    const float* ctx1       = (const float*)d_in[4];
    const int*   ebev       = (const int*)d_in[5];
    const float* cov        = (const float*)d_in[7];
    const float* embed      = (const float*)d_in[8];
    const float* ln_g       = (const float*)d_in[9];
    const float* ln_b       = (const float*)d_in[10];
    const float* xc_W       = (const float*)d_in[11];
    const float* xc_b       = (const float*)d_in[12];
    const float* W_ih       = (const float*)d_in[13];
    const float* W_hh       = (const float*)d_in[14];
    const float* b_ih       = (const float*)d_in[15];
    const float* b_hh       = (const float*)d_in[16];
    const float* Wh         = (const float*)d_in[17];
    const float* Ws         = (const float*)d_in[18];
    const float* Ws_b       = (const float*)d_in[19];
    const float* Wc         = (const float*)d_in[20];
    const float* Vv         = (const float*)d_in[21];
    const float* pg_W       = (const float*)d_in[22];
    const float* pg_b       = (const float*)d_in[23];
    const float* out1_W     = (const float*)d_in[24];
    const float* out1_b     = (const float*)d_in[25];
    const float* out2_W     = (const float*)d_in[26];
    const float* out2_b     = (const float*)d_in[27];

    float* out      = (float*)d_out;
    float* s_t      = out + 6464000;
    float* h_t      = out + 6595072;
    float* cov_next = out + 6726144;
    float* loss     = out + 6791680;

    const size_t ENC_SLOTS = 33554432, WH_SLOTS = 524288;
    const size_t BASE_SLOTS = 5178496;
    const size_t need = (ENC_SLOTS + WH_SLOTS + BASE_SLOTS) * 4;
    const bool bf16_path = (ws_size >= need);

    float* wsf = (float*)d_ws;
    unsigned short* enc_bf = (unsigned short*)d_ws;
    unsigned short* wh_bf  = (unsigned short*)(wsf + ENC_SLOTS);
    float* base     = bf16_path ? (wsf + ENC_SLOTS + WH_SLOTS) : wsf;
    float* x_cat    = base;             // 262144
    float* x_part   = base + 262144;    // 4 x 131072
    float* x        = base + 786432;    // 131072
    float* gx_part  = base + 917504;    // 2 x 393216
    float* gh_part  = base + 1703936;   // 2 x 393216
    float* ds_part  = base + 2490368;   // 4 x 131072
    float* e_part   = base + 3145728;   // 8 x 65536
    float* att      = base + 3670016;   // 65536
    float* pgen     = base + 3735552;   // 128
    float* A2       = base + 3735680;   // 262144
    float* h2_part  = base + 3997824;   // 4 x 131072
    float* h2       = base + 4522112;   // 131072
    float* hq       = base + 4653184;   // 4 x 131072 (end = 5177472)
    float2* mpart   = (float2*)(base + 5177472);  // 128 x 4 float2

    if (bf16_path) {
        cvt2_bf16_kernel<<<33280, 256, 0, stream>>>(enc, Wh, enc_bf, wh_bf);
    }
    embed_ln_kernel<<<128, 256, 0, stream>>>(tok, embed, ln_g, ln_b, ctx1, x_cat);
    gemm128_kernel<<<dim3(16,4), 256, 0, stream>>>(x_cat, xc_W, xc_b, x_part, 1024, 2048, 1024, 512);
    reduce4_kernel<<<512, 256, 0, stream>>>(x_part, x, 131072);
    gemm128_dual_kernel<<<dim3(48,2,2), 256, 0, stream>>>(
        x, W_ih, b_ih, gx_part,
        dec_hidden, W_hh, b_hh, gh_part, 3072, 1024, 3072, 512);
    gru_gate_kernel<<<512, 256, 0, stream>>>(gx_part, gh_part, dec_hidden, s_t);
    gemm128_kernel<<<dim3(16,4), 256, 0, stream>>>(s_t, Ws, Ws_b, ds_part, 1024, 1024, 1024, 256);

    if (bf16_path) {
        attn_gemm_bf16_kernel<<<4096, 256, 0, stream>>>(enc_bf, wh_bf, ds_part, cov, Wc, Vv, e_part);
        dim3 g8(128, 4);
        smax_ctx_bf16_kernel<<<g8, 256, 0, stream>>>(e_part, mask, cov, enc_bf,
                                                     att, cov_next, loss, hq);
    } else {
        attn_gemm_f32_kernel<<<2048, 512, 0, stream>>>(enc, Wh, ds_part, cov, Wc, Vv, e_part);
        attn_softmax_kernel<<<128, 256, 0, stream>>>(e_part, 4, mask, cov, att, cov_next, loss);
        dim3 g8(128, 8);
        context_part_f32_kernel<<<g8, 256, 0, stream>>>(att, enc, hq);
    }
    pgen_kernel<<<128, 256, 0, stream>>>(hq, s_t, x, pg_W, pg_b, pgen, h_t, A2);
    gemm128_kernel<<<dim3(16,4), 256, 0, stream>>>(A2, out1_W, out1_b, h2_part, 1024, 2048, 1024, 512);
    reduce4_kernel<<<512, 256, 0, stream>>>(h2_part, h2, 131072);

    gemm128_kernel<<<dim3(782,1), 256, 0, stream>>>(h2, out2_W, out2_b, out, 50000, 1024, VE_, 1024);
    vocab_pass1_kernel<<<dim3(128,4), 256, 0, stream>>>(out, mpart);
    vocab_pass2_kernel<<<dim3(128,4), 256, 0, stream>>>(out, mpart, pgen, ebev, att, out);
}